// Round 5
// baseline (12183.546 us; speedup 1.0000x reference)
//
#include <hip/hip_runtime.h>
#include <hip/hip_cooperative_groups.h>
#include <math.h>

#define TT 400
#define BBATCH 256
#define VDIM 128
#define CDIM 64
#define HDIM 512
#define KB 32
#define NCHUNK 22

namespace cg = cooperative_groups;

typedef double d4 __attribute__((ext_vector_type(4)));

__device__ __forceinline__ double sigd(double x) {
  if (x >= 0.0) { double e = exp(-x); return 1.0 / (1.0 + e); }
  double e = exp(x); return e / (1.0 + e);
}

// transpose W_out / W_ctrl to [k][c] for coalesced phase-2 loads
__global__ __launch_bounds__(256) void k_init(
    float* __restrict__ wtro, const float* __restrict__ W_out,
    float* __restrict__ wtrc, const float* __restrict__ W_ctrl)
{
  const int i = blockIdx.x * 256 + threadIdx.x;
  if (i < HDIM * CDIM) {
    const int k = i >> 6, c = i & 63;
    wtro[i] = W_out[c * HDIM + k];
  }
  if (i < 577 * CDIM) {
    const int k = i >> 6, c = i & 63;
    wtrc[i] = W_ctrl[c * 577 + k];
  }
}

// Persistent fused kernel: 256 blocks x 256 threads, 1 block/CU.
// Per step: phase1 (block = GEMM tile (cb,rb)) -> grid.sync ->
//           phase2 (block = batch row bid)     -> grid.sync.
// Breaks out of the t-loop once every (b,c) has halted.
__global__ __launch_bounds__(256, 1) void k_fused(
    const float* __restrict__ X, const float* __restrict__ W_ih,
    const float* __restrict__ W_hh, const float* __restrict__ b_ih,
    const float* __restrict__ b_hh, const float* __restrict__ wtro,
    const float* __restrict__ b_out, const float* __restrict__ wtrc,
    const float* __restrict__ b_ctrl, const float* __restrict__ noise,
    const int* __restrict__ epoch_p,
    double* __restrict__ h0buf, double* __restrict__ h1buf,
    double* __restrict__ ybar, int* __restrict__ rowflag,
    double* __restrict__ partial, float* __restrict__ out)
{
  cg::grid_group grid = cg::this_grid();

  __shared__ __align__(16) double aF[2][4][8][64];   // 32 KB (g_s aliased in)
  __shared__ __align__(16) double bF[2][2][8][64];   // 16 KB (phase2 bufs aliased in)
  __shared__ double red[256];

  double (*g_s)[33] = (double(*)[33])&aF[0][0][0][0];   // 64x33 = 16.9 KB <= 32 KB
  double* hsh = &bF[0][0][0][0];                        // 512
  double* psh = hsh + HDIM;                             // 4*64
  double* ysh = psh + 256;                              // 64  (6.7 KB <= 16 KB)

  const int tid   = threadIdx.x;
  const int lane  = tid & 63;
  const int wid   = tid >> 6;
  const int bid   = blockIdx.x;
  const int cb    = bid & 63;
  const int rb    = bid >> 6;
  const int r0    = rb * 64;
  const int hbase = cb * 8;

  const int sk = (tid & 7) * 4;     // staging k offset
  const int sr = tid >> 3;          // 0..31
  const int s  = sk >> 2;           // k-step slot
  const int wg = (sr >> 3) * HDIM + hbase + (sr & 7);

  // Empirical f64-MFMA D-layout probe (once): A[i][0]=i+1,A[i][1]=1,
  // B[0][j]=1,B[1][j]=1000(j+1) => D[i][j]=(i+1)+1000(j+1).
  int rowm[4], colm[4];
  {
    d4 dp = {0.0, 0.0, 0.0, 0.0};
    const double ap = (lane < 16) ? (double)(lane + 1) : (lane < 32 ? 1.0 : 0.0);
    const double bp = (lane < 16) ? 1.0
                    : (lane < 32 ? 1000.0 * (double)((lane & 15) + 1) : 0.0);
    dp = __builtin_amdgcn_mfma_f64_16x16x4f64(ap, bp, dp, 0, 0, 0);
    #pragma unroll
    for (int r = 0; r < 4; ++r) {
      const int iv = (int)(dp[r] + 0.5);
      rowm[r] = ((iv % 1000) - 1) & 15;
      colm[r] = ((iv / 1000) - 1) & 15;
    }
  }

  // hoisted bias sums for the cell epilogue (thread-stable mapping)
  double bsum[2][4];
  #pragma unroll
  for (int q = 0; q < 2; ++q) {
    const int g0 = hbase + ((tid + q * 256) & 7);
    #pragma unroll
    for (int g = 0; g < 4; ++g)
      bsum[q][g] = (double)b_ih[g * HDIM + g0] + (double)b_hh[g * HDIM + g0];
  }

  // persistent per-thread state
  double c_st[2] = {0.0, 0.0};                  // LSTM cell state (phase1 tile)
  double pred_r = 0.0, ybar_r = 0.0, ylast_r = 0.0;  // phase2 row state (wave 0)
  float  halt_r = -1.0f;
  const double eps = exp(-7.0 * (double)(*epoch_p) / 99.0);

  double pa[2][4];
  float  pw[4];

  for (int t = 0; t < TT; ++t) {
    bool grp_ok = true;
    if (t > 0) {
      const int f0 = rowflag[lane],       f1 = rowflag[64 + lane];
      const int f2 = rowflag[128 + lane], f3 = rowflag[192 + lane];
      if (__ballot((f0 | f1 | f2 | f3) != 0) == 0ull) break;  // all halted
      const int fg = (rb == 0) ? f0 : (rb == 1) ? f1 : (rb == 2) ? f2 : f3;
      grp_ok = (__ballot(fg != 0) != 0ull);
    }

    const double* hR = (t & 1) ? h1buf : h0buf;
    double*       hW = (t & 1) ? h0buf : h1buf;

    if (grp_ok) {
      auto load_chunk = [&](int ci) {
        const int kk = ci * KB + sk;
        #pragma unroll
        for (int hf = 0; hf < 2; ++hf) {
          const int rr = r0 + sr + hf * 32;
          if (kk < VDIM) {
            const float4 v = *(const float4*)(X + ((size_t)t * BBATCH + rr) * VDIM + kk);
            pa[hf][0] = v.x; pa[hf][1] = v.y; pa[hf][2] = v.z; pa[hf][3] = v.w;
          } else if (t == 0) {
            pa[hf][0] = 0.0; pa[hf][1] = 0.0; pa[hf][2] = 0.0; pa[hf][3] = 0.0;
          } else if (kk < VDIM + CDIM) {
            const double2 v0 = *(const double2*)(ybar + (size_t)rr * CDIM + (kk - VDIM));
            const double2 v1 = *(const double2*)(ybar + (size_t)rr * CDIM + (kk - VDIM) + 2);
            pa[hf][0] = v0.x; pa[hf][1] = v0.y; pa[hf][2] = v1.x; pa[hf][3] = v1.y;
          } else {
            const double2 v0 = *(const double2*)(hR + (size_t)rr * HDIM + (kk - 192));
            const double2 v1 = *(const double2*)(hR + (size_t)rr * HDIM + (kk - 192) + 2);
            pa[hf][0] = v0.x; pa[hf][1] = v0.y; pa[hf][2] = v1.x; pa[hf][3] = v1.y;
          }
        }
        const float4 wv = (kk < 192)
          ? *(const float4*)(W_ih + (size_t)wg * 192 + kk)
          : *(const float4*)(W_hh + (size_t)wg * HDIM + (kk - 192));
        pw[0] = wv.x; pw[1] = wv.y; pw[2] = wv.z; pw[3] = wv.w;
      };
      auto store_chunk = [&](int buf) {
        #pragma unroll
        for (int hf = 0; hf < 2; ++hf) {
          const int rl = sr + hf * 32;
          const int rt = rl >> 4, rr = rl & 15;
          #pragma unroll
          for (int j = 0; j < 4; ++j)
            aF[buf][rt][s][16 * j + rr] = pa[hf][j];
        }
        const int ct = sr >> 4, cl = sr & 15;
        #pragma unroll
        for (int j = 0; j < 4; ++j)
          bF[buf][ct][s][16 * j + cl] = (double)pw[j];
      };

      d4 a0a = {0.0, 0.0, 0.0, 0.0}, a0b = a0a, a1a = a0a, a1b = a0a;

      load_chunk(0);
      store_chunk(0);
      __syncthreads();

      for (int ci = 0; ci < NCHUNK; ++ci) {
        const int p = ci & 1;
        if (ci + 1 < NCHUNK) load_chunk(ci + 1);
        #pragma unroll
        for (int ss = 0; ss < 8; ++ss) {
          const double av = aF[p][wid][ss][lane];
          const double b0 = bF[p][0][ss][lane];
          const double b1 = bF[p][1][ss][lane];
          if (ss & 1) {
            a0b = __builtin_amdgcn_mfma_f64_16x16x4f64(av, b0, a0b, 0, 0, 0);
            a1b = __builtin_amdgcn_mfma_f64_16x16x4f64(av, b1, a1b, 0, 0, 0);
          } else {
            a0a = __builtin_amdgcn_mfma_f64_16x16x4f64(av, b0, a0a, 0, 0, 0);
            a1a = __builtin_amdgcn_mfma_f64_16x16x4f64(av, b1, a1a, 0, 0, 0);
          }
        }
        if (ci + 1 < NCHUNK) store_chunk(p ^ 1);
        __syncthreads();
      }
      const d4 acc0 = a0a + a0b;
      const d4 acc1 = a1a + a1b;

      #pragma unroll
      for (int r = 0; r < 4; ++r) {
        g_s[16 * wid + rowm[r]][colm[r]]      = acc0[r];
        g_s[16 * wid + rowm[r]][16 + colm[r]] = acc1[r];
      }
      __syncthreads();

      #pragma unroll
      for (int q = 0; q < 2; ++q) {
        const int idx = tid + q * 256;
        const int jj = idx & 7, r = idx >> 3;
        const double gi = g_s[r][jj]      + bsum[q][0];
        const double gf = g_s[r][8 + jj]  + bsum[q][1];
        const double gg = g_s[r][16 + jj] + bsum[q][2];
        const double go = g_s[r][24 + jj] + bsum[q][3];
        const double cn = sigd(gf) * c_st[q] + sigd(gi) * tanh(gg);
        const double hn = sigd(go) * tanh(cn);
        c_st[q] = cn;
        hW[(size_t)(r0 + r) * HDIM + hbase + jj] = hn;
      }
    }

    grid.sync();

    // ---------------- phase 2: row bid ----------------
    const bool row_ok = (t == 0) || (rowflag[bid] != 0);
    if (row_ok) {
      *(double2*)&hsh[2 * tid] = *(const double2*)(hW + (size_t)bid * HDIM + 2 * tid);
      __syncthreads();

      const int c = lane, kq = wid;
      const int k0 = kq * 128;

      double s1 = 0.0;
      #pragma unroll 8
      for (int k = k0; k < k0 + 128; ++k)
        s1 += hsh[k] * (double)wtro[k * 64 + c];
      psh[kq * 64 + c] = s1;
      __syncthreads();

      if (tid < 64)
        ysh[tid] = sigd(psh[tid] + psh[64 + tid] + psh[128 + tid] + psh[192 + tid]
                        + (double)b_out[tid]);
      __syncthreads();

      double s2 = 0.0;
      #pragma unroll 8
      for (int k = k0; k < k0 + 128; ++k)
        s2 += hsh[k] * (double)wtrc[k * 64 + c];
      if (kq == 0) {
        #pragma unroll 8
        for (int j = 0; j < 64; ++j)
          s2 += ysh[j] * (double)wtrc[(512 + j) * 64 + c];
        s2 += (double)t * (double)wtrc[576 * 64 + c] + (double)b_ctrl[c];
      }
      psh[kq * 64 + c] = s2;
      __syncthreads();

      bool pz = false;
      if (tid < 64) {
        const double a2 = psh[tid] + psh[64 + tid] + psh[128 + tid] + psh[192 + tid];
        const double pr = (1.0 - eps) * sigd(a2) + eps * 0.05;
        const double n  = (double)noise[((size_t)t * BBATCH + bid) * CDIM + tid];
        const bool at = n < pr;
        const double yh = ysh[tid];
        const bool was_zero = (pred_r == 0.0);
        if (at && was_zero) pred_r = yh;
        if (at && ybar_r == 0.0) ybar_r = 1.0;
        if (halt_r == -1.0f && at) halt_r = (float)t;
        ylast_r = yh;
        pz = was_zero && !at;
        ybar[(size_t)bid * CDIM + tid] = ybar_r;
      }
      const unsigned long long m = __ballot(pz);
      if (tid == 0) rowflag[bid] = (m != 0ull) ? 1 : 0;
    }

    grid.sync();
  }

  // ---------------- epilogue ----------------
  if (tid < 64) {
    out[(size_t)bid * CDIM + tid] = (float)(pred_r == 0.0 ? ylast_r : pred_r);
    double hv = 1.0 + ((halt_r == -1.0f) ? (double)(TT - 1) : (double)halt_r);
    #pragma unroll
    for (int off = 32; off > 0; off >>= 1)
      hv += __shfl_down(hv, off, 64);
    if (tid == 0) partial[bid] = hv;
  }
  grid.sync();
  if (bid == 0) {
    red[tid] = partial[tid];
    __syncthreads();
    for (int off = 128; off > 0; off >>= 1) {
      if (tid < off) red[tid] += red[tid + off];
      __syncthreads();
    }
    if (tid == 0)
      out[BBATCH * CDIM] = (float)(red[0] / (double)(BBATCH * CDIM) / (double)(TT + 1));
  }
}

extern "C" void kernel_launch(void* const* d_in, const int* in_sizes, int n_in,
                              void* d_out, int out_size, void* d_ws, size_t ws_size,
                              hipStream_t stream)
{
  const float* X      = (const float*)d_in[0];
  const float* noise  = (const float*)d_in[1];
  const float* W_ih   = (const float*)d_in[2];
  const float* W_hh   = (const float*)d_in[3];
  const float* b_ih   = (const float*)d_in[4];
  const float* b_hh   = (const float*)d_in[5];
  const float* W_out  = (const float*)d_in[6];
  const float* b_out  = (const float*)d_in[7];
  const float* W_ctrl = (const float*)d_in[8];
  const float* b_ctrl = (const float*)d_in[9];
  const int*   epoch  = (const int*)d_in[10];
  float* out = (float*)d_out;

  char* ws = (char*)d_ws;
  double* h0      = (double*)ws;
  double* h1      = h0      + (size_t)BBATCH * HDIM;
  double* ybar    = h1      + (size_t)BBATCH * HDIM;
  double* partial = ybar    + (size_t)BBATCH * CDIM;
  float*  wtro    = (float*)(partial + BBATCH);
  float*  wtrc    = wtro + (size_t)HDIM * CDIM;
  int*    rowflag = (int*)(wtrc + (size_t)577 * CDIM);

  k_init<<<145, 256, 0, stream>>>(wtro, W_out, wtrc, W_ctrl);

  void* args[] = {
    (void*)&X, (void*)&W_ih, (void*)&W_hh, (void*)&b_ih, (void*)&b_hh,
    (void*)&wtro, (void*)&b_out, (void*)&wtrc, (void*)&b_ctrl, (void*)&noise,
    (void*)&epoch, (void*)&h0, (void*)&h1, (void*)&ybar, (void*)&rowflag,
    (void*)&partial, (void*)&out
  };
  hipLaunchCooperativeKernel((const void*)k_fused, dim3(256), dim3(256),
                             args, 0, stream);
}

// Round 6
// 4585.688 us; speedup vs baseline: 2.6569x; 2.6569x over previous
//
#include <hip/hip_runtime.h>
#include <math.h>

#define TT 400
#define BBATCH 256
#define VDIM 128
#define CDIM 64
#define HDIM 512
#define KB 32
#define NCHUNK 22

typedef double d4 __attribute__((ext_vector_type(4)));

__device__ __forceinline__ double sigd(double x) {
  if (x >= 0.0) { double e = exp(-x); return 1.0 / (1.0 + e); }
  double e = exp(x); return e / (1.0 + e);
}

// transpose W_out/W_ctrl to [k][c]; init rowlive/alive. All other state is
// (re)initialized inside the step kernels via t==0 guards.
__global__ __launch_bounds__(256) void k_init(
    float* __restrict__ wtro, const float* __restrict__ W_out,
    float* __restrict__ wtrc, const float* __restrict__ W_ctrl,
    int* __restrict__ rowlive, int* __restrict__ alive)
{
  const int i = blockIdx.x * 256 + threadIdx.x;
  if (i < HDIM * CDIM) {
    const int k = i >> 6, c = i & 63;
    wtro[i] = W_out[c * HDIM + k];
  }
  if (i < 577 * CDIM) {
    const int k = i >> 6, c = i & 63;
    wtrc[i] = W_ctrl[c * 577 + k];
  }
  if (i < BBATCH) rowlive[i] = 1;
  if (i < TT) alive[i] = 0;
}

// Phase 1: gates GEMM (f64 MFMA) + fused LSTM cell.
// Grid (64, 8): 64 col-blocks (8 hidden x 4 gates) x 8 row-blocks of 32 rows.
// 42 KB LDS -> 2 blocks/CU for cross-block overlap of staging and MFMA.
__global__ __launch_bounds__(256) void k_phase1(
    const float* __restrict__ X, const float* __restrict__ W_ih,
    const float* __restrict__ W_hh, const float* __restrict__ b_ih,
    const float* __restrict__ b_hh, const double* __restrict__ hR,
    double* __restrict__ hW, double* __restrict__ cst,
    const double* __restrict__ ybar, const int* __restrict__ rowlive,
    const int* __restrict__ alive, int t)
{
  if (t > 0 && alive[t - 1] == 0) return;      // everything halted: dead step

  const int tid  = threadIdx.x;
  const int lane = tid & 63;
  const int wid  = tid >> 6;
  const int cb   = blockIdx.x;
  const int rb   = blockIdx.y;
  const int r0   = rb * 32;
  const int hbase = cb * 8;

  // 32-row block skip: all rows halted -> no output of this block is ever read
  if (t > 0) {
    const unsigned long long m =
        __ballot((lane < 32) && (rowlive[r0 + (lane & 31)] != 0));
    if (m == 0ull) return;
  }

  // fragment staging, k-slot stride padded 64->66 to break write bank conflicts
  __shared__ __align__(16) double aF[2][2][8][66];   // 16.9 KB
  __shared__ __align__(16) double bF[2][2][8][66];   // 16.9 KB
  __shared__ __align__(16) double g_s[32][33];       //  8.4 KB

  const int sk = (tid & 7) * 4;     // k offset within chunk
  const int sr = tid >> 3;          // 0..31: A-row / B-col
  const int s  = tid & 7;           // k-slot
  const int srt = sr >> 4, srr = sr & 15;
  const int wg = (sr >> 3) * HDIM + hbase + (sr & 7);  // W row for staged col sr

  // Empirical f64-MFMA D-layout probe: A[i][0]=i+1,A[i][1]=1,B[0][j]=1,
  // B[1][j]=1000(j+1) => D[i][j]=(i+1)+1000(j+1); decode reg->row/col.
  int rowm[4], colm[4];
  {
    d4 dp = {0.0, 0.0, 0.0, 0.0};
    const double ap = (lane < 16) ? (double)(lane + 1) : (lane < 32 ? 1.0 : 0.0);
    const double bp = (lane < 16) ? 1.0
                    : (lane < 32 ? 1000.0 * (double)((lane & 15) + 1) : 0.0);
    dp = __builtin_amdgcn_mfma_f64_16x16x4f64(ap, bp, dp, 0, 0, 0);
    #pragma unroll
    for (int r = 0; r < 4; ++r) {
      const int iv = (int)(dp[r] + 0.5);
      rowm[r] = ((iv % 1000) - 1) & 15;
      colm[r] = ((iv / 1000) - 1) & 15;
    }
  }

  double pa[4];
  float  pw[4];

  auto load_chunk = [&](int ci) {
    const int kk = ci * KB + sk;
    const int rr = r0 + sr;
    if (kk < VDIM) {
      const float4 v = *(const float4*)(X + ((size_t)t * BBATCH + rr) * VDIM + kk);
      pa[0] = v.x; pa[1] = v.y; pa[2] = v.z; pa[3] = v.w;
    } else if (t == 0) {
      pa[0] = 0.0; pa[1] = 0.0; pa[2] = 0.0; pa[3] = 0.0;
    } else if (kk < VDIM + CDIM) {
      const double2 v0 = *(const double2*)(ybar + (size_t)rr * CDIM + (kk - VDIM));
      const double2 v1 = *(const double2*)(ybar + (size_t)rr * CDIM + (kk - VDIM) + 2);
      pa[0] = v0.x; pa[1] = v0.y; pa[2] = v1.x; pa[3] = v1.y;
    } else {
      const double2 v0 = *(const double2*)(hR + (size_t)rr * HDIM + (kk - 192));
      const double2 v1 = *(const double2*)(hR + (size_t)rr * HDIM + (kk - 192) + 2);
      pa[0] = v0.x; pa[1] = v0.y; pa[2] = v1.x; pa[3] = v1.y;
    }
    const float4 wv = (kk < 192)
      ? *(const float4*)(W_ih + (size_t)wg * 192 + kk)
      : *(const float4*)(W_hh + (size_t)wg * HDIM + (kk - 192));
    pw[0] = wv.x; pw[1] = wv.y; pw[2] = wv.z; pw[3] = wv.w;
  };
  auto store_chunk = [&](int buf) {
    #pragma unroll
    for (int j = 0; j < 4; ++j)
      aF[buf][srt][s][16 * j + srr] = pa[j];
    #pragma unroll
    for (int j = 0; j < 4; ++j)
      bF[buf][srt][s][16 * j + srr] = (double)pw[j];
  };

  const int rt = wid >> 1, ct = wid & 1;   // wave's 16x16 output tile
  d4 aa = {0.0, 0.0, 0.0, 0.0}, ab = aa;

  load_chunk(0);
  store_chunk(0);
  __syncthreads();

  // single barrier per chunk: store(p^1) races only with reads of p^1 in the
  // PREVIOUS iteration, which the previous barrier already ordered.
  for (int ci = 0; ci < NCHUNK; ++ci) {
    const int p = ci & 1;
    if (ci + 1 < NCHUNK) load_chunk(ci + 1);
    #pragma unroll
    for (int ss = 0; ss < 8; ++ss) {
      const double av = aF[p][rt][ss][lane];
      const double bv = bF[p][ct][ss][lane];
      if (ss & 1) ab = __builtin_amdgcn_mfma_f64_16x16x4f64(av, bv, ab, 0, 0, 0);
      else        aa = __builtin_amdgcn_mfma_f64_16x16x4f64(av, bv, aa, 0, 0, 0);
    }
    if (ci + 1 < NCHUNK) store_chunk(p ^ 1);
    __syncthreads();
  }
  const d4 acc = aa + ab;

  #pragma unroll
  for (int r = 0; r < 4; ++r)
    g_s[16 * rt + rowm[r]][16 * ct + colm[r]] = acc[r];
  __syncthreads();

  // LSTM cell: 32 rows x 8 hidden = 256 pairs, 1/thread; 8 consecutive lanes
  // = 8 consecutive hidden units -> 64B-contiguous global accesses.
  {
    const int jj = tid & 7, r = tid >> 3;
    const int g0 = hbase + jj;
    const double gi = g_s[r][jj]      + (double)b_ih[0 * HDIM + g0] + (double)b_hh[0 * HDIM + g0];
    const double gf = g_s[r][8 + jj]  + (double)b_ih[1 * HDIM + g0] + (double)b_hh[1 * HDIM + g0];
    const double gg = g_s[r][16 + jj] + (double)b_ih[2 * HDIM + g0] + (double)b_hh[2 * HDIM + g0];
    const double go = g_s[r][24 + jj] + (double)b_ih[3 * HDIM + g0] + (double)b_hh[3 * HDIM + g0];
    const size_t oidx = (size_t)(r0 + r) * HDIM + g0;
    const double cold = (t == 0) ? 0.0 : cst[oidx];
    const double cn = sigd(gf) * cold + sigd(gi) * tanh(gg);
    const double hn = sigd(go) * tanh(cn);
    cst[oidx] = cn;
    hW[oidx]  = hn;
  }
}

// Phase 2: one batch row per block; fused dual GEMV; row-level skip.
__global__ __launch_bounds__(256) void k_phase2(
    const double* __restrict__ h, const float* __restrict__ wtro,
    const float* __restrict__ b_out, const float* __restrict__ wtrc,
    const float* __restrict__ b_ctrl, const float* __restrict__ noise,
    const int* __restrict__ epoch_p, double* __restrict__ ybar,
    double* __restrict__ preds, float* __restrict__ halt,
    double* __restrict__ ylast, int* __restrict__ rowlive,
    int* __restrict__ alive, int t)
{
  const int tid = threadIdx.x;
  const int b   = blockIdx.x;
  if (t > 0 && rowlive[b] == 0) return;

  __shared__ double hsh[HDIM];
  __shared__ double p1[4][64];
  __shared__ double p2[4][64];
  __shared__ double ysh[64];

  *(double2*)&hsh[2 * tid] = *(const double2*)(h + (size_t)b * HDIM + 2 * tid);
  __syncthreads();

  const int c = tid & 63, kq = tid >> 6;
  const int k0 = kq * 128;

  double s1 = 0.0, s2 = 0.0;
  #pragma unroll 8
  for (int k = k0; k < k0 + 128; ++k) {
    const double hk = hsh[k];
    s1 += hk * (double)wtro[k * 64 + c];
    s2 += hk * (double)wtrc[k * 64 + c];
  }
  p1[kq][c] = s1;
  p2[kq][c] = s2;
  __syncthreads();

  if (tid < 64)
    ysh[tid] = sigd(p1[0][tid] + p1[1][tid] + p1[2][tid] + p1[3][tid]
                    + (double)b_out[tid]);
  __syncthreads();

  if (tid < 64) {
    double a2 = p2[0][tid] + p2[1][tid] + p2[2][tid] + p2[3][tid];
    #pragma unroll 8
    for (int j = 0; j < CDIM; ++j)
      a2 += ysh[j] * (double)wtrc[(512 + j) * 64 + tid];
    a2 += (double)t * (double)wtrc[576 * 64 + tid] + (double)b_ctrl[tid];

    const double eps = exp(-7.0 * (double)(*epoch_p) / 99.0);
    const double pr  = (1.0 - eps) * sigd(a2) + eps * 0.05;
    const double n   = (double)noise[((size_t)t * BBATCH + b) * CDIM + tid];
    const bool   at  = n < pr;
    const double yh  = ysh[tid];
    const size_t i   = (size_t)b * CDIM + tid;

    const double pred_old = (t == 0) ? 0.0  : preds[i];
    const double ybar_old = (t == 0) ? 0.0  : ybar[i];
    const float  halt_old = (t == 0) ? -1.0f : halt[i];

    const double pred_new = (at && pred_old == 0.0) ? yh : pred_old;
    preds[i] = pred_new;
    ybar[i]  = (at && ybar_old == 0.0) ? 1.0 : ybar_old;
    halt[i]  = (halt_old == -1.0f && at) ? (float)t : halt_old;
    ylast[i] = yh;

    const unsigned long long m = __ballot(pred_new == 0.0);
    if (tid == 0) {
      rowlive[b] = (m != 0ull) ? 1 : 0;
      if (m != 0ull) atomicOr(alive + t, 1);
    }
  }
}

__global__ __launch_bounds__(256) void k_final_out(
    const double* __restrict__ preds, const double* __restrict__ ylast,
    float* __restrict__ out)
{
  const int i = blockIdx.x * 256 + threadIdx.x;
  const double p = preds[i];
  out[i] = (float)(p == 0.0 ? ylast[i] : p);
}

__global__ __launch_bounds__(256) void k_final_mean(
    const float* __restrict__ halt, float* __restrict__ out)
{
  __shared__ double s[256];
  double acc = 0.0;
  for (int i = threadIdx.x; i < BBATCH * CDIM; i += 256) {
    const float hp = halt[i];
    acc += 1.0 + (hp == -1.0f ? (double)(TT - 1) : (double)hp);
  }
  s[threadIdx.x] = acc;
  __syncthreads();
  for (int off = 128; off > 0; off >>= 1) {
    if (threadIdx.x < off) s[threadIdx.x] += s[threadIdx.x + off];
    __syncthreads();
  }
  if (threadIdx.x == 0)
    out[BBATCH * CDIM] = (float)(s[0] / (double)(BBATCH * CDIM) / (double)(TT + 1));
}

extern "C" void kernel_launch(void* const* d_in, const int* in_sizes, int n_in,
                              void* d_out, int out_size, void* d_ws, size_t ws_size,
                              hipStream_t stream)
{
  const float* X      = (const float*)d_in[0];
  const float* noise  = (const float*)d_in[1];
  const float* W_ih   = (const float*)d_in[2];
  const float* W_hh   = (const float*)d_in[3];
  const float* b_ih   = (const float*)d_in[4];
  const float* b_hh   = (const float*)d_in[5];
  const float* W_out  = (const float*)d_in[6];
  const float* b_out  = (const float*)d_in[7];
  const float* W_ctrl = (const float*)d_in[8];
  const float* b_ctrl = (const float*)d_in[9];
  const int*   epoch  = (const int*)d_in[10];
  float* out = (float*)d_out;

  char* ws = (char*)d_ws;
  double* h0      = (double*)ws;
  double* h1      = h0    + (size_t)BBATCH * HDIM;
  double* cst     = h1    + (size_t)BBATCH * HDIM;
  double* ybar    = cst   + (size_t)BBATCH * HDIM;
  double* preds   = ybar  + (size_t)BBATCH * CDIM;
  double* ylast   = preds + (size_t)BBATCH * CDIM;
  float*  halt    = (float*)(ylast + (size_t)BBATCH * CDIM);
  float*  wtro    = halt + (size_t)BBATCH * CDIM;
  float*  wtrc    = wtro + (size_t)HDIM * CDIM;
  int*    rowlive = (int*)(wtrc + (size_t)577 * CDIM);
  int*    alive   = rowlive + BBATCH;

  k_init<<<145, 256, 0, stream>>>(wtro, W_out, wtrc, W_ctrl, rowlive, alive);

  for (int t = 0; t < TT; ++t) {
    const double* hR = (t & 1) ? h1 : h0;
    double*       hW = (t & 1) ? h0 : h1;
    k_phase1<<<dim3(64, 8), 256, 0, stream>>>(X, W_ih, W_hh, b_ih, b_hh,
                                              hR, hW, cst, ybar, rowlive, alive, t);
    k_phase2<<<BBATCH, 256, 0, stream>>>(hW, wtro, b_out, wtrc, b_ctrl, noise,
                                         epoch, ybar, preds, halt, ylast,
                                         rowlive, alive, t);
  }

  k_final_out<<<64, 256, 0, stream>>>(preds, ylast, out);
  k_final_mean<<<1, 256, 0, stream>>>(halt, out);
}